// Round 14
// baseline (118.368 us; speedup 1.0000x reference)
//
#include <hip/hip_runtime.h>
#include <math.h>

#define IN_DIM 128
#define HID 64
#define NPB 128            // nodes per bucket
#define NPB_SH 7
#define CAP 4096           // sorted-pairs capacity per bucket (mean 2048)
#define CHUNK 1024         // edges per binning block
#define SLDS 1024          // gather1 LDS pair-stage capacity (quarter-bucket)

typedef __attribute__((ext_vector_type(8))) short bf16x8;
typedef __attribute__((ext_vector_type(4))) float f32x4;
typedef __attribute__((ext_vector_type(4))) _Float16 f16x4;

static __device__ inline short f2bf(float f) {
    unsigned u = __float_as_uint(f);
    u += 0x7fff + ((u >> 16) & 1);          // RNE
    return (short)(u >> 16);
}

// tanh via v_exp + v_rcp: ~5 VALU instrs, err ~1e-6 (vs library tanhf)
static __device__ inline float fast_tanh(float x) {
    float e = __expf(x * 2.0f);
    return 1.0f - 2.0f * __builtin_amdgcn_rcpf(e + 1.0f);
}

// ------- pack W1 [128][64] f32 -> bf16 MFMA B-fragment order -------------
__global__ void k_packW(const float* __restrict__ W1, ushort* __restrict__ W1p) {
    int idx = blockIdx.x * 256 + threadIdx.x;        // 0..8191
    int i = idx & 7, lane = (idx >> 3) & 63, fb = (idx >> 9) & 3, kc = (idx >> 11) & 3;
    int k = kc * 32 + (lane >> 4) * 8 + i;
    int f = fb * 16 + (lane & 15);
    W1p[idx] = (ushort)f2bf(W1[k * HID + f]);
}

// ---- binning: 256 thr, 1024 edges; counting-sort by bucket; coalesced ---
__global__ void __launch_bounds__(256) k_binpairs(
        const int* __restrict__ row, const int* __restrict__ col,
        unsigned* __restrict__ pairsA, unsigned short* __restrict__ chk,
        int E, int nbuk) {
    __shared__ unsigned cntL[1024];
    __shared__ unsigned offs[1024];
    __shared__ unsigned wsum[4];
    __shared__ unsigned stage[CHUNK];
    int t = threadIdx.x;
    int base = blockIdx.x * CHUNK;
    int cc = min(CHUNK, E - base);

    for (int i = t; i < nbuk; i += 256) cntL[i] = 0;
    __syncthreads();

    unsigned myPk[4], myR[4];
    int myB[4];
#pragma unroll
    for (int i = 0; i < 4; ++i) {
        int j = i * 256 + t;
        myB[i] = -1;
        if (j < cc) {
            int r = row[base + j], c = col[base + j];
            int b = c >> NPB_SH;
            myR[i] = atomicAdd(&cntL[b], 1u);
            myPk[i] = (unsigned)r | ((unsigned)(c & (NPB - 1)) << 24);
            myB[i] = b;
        }
    }
    __syncthreads();
    // exclusive scan, 4 bins per thread
    unsigned cb[4];
#pragma unroll
    for (int k = 0; k < 4; ++k) {
        int bb = 4 * t + k;
        cb[k] = (bb < nbuk) ? cntL[bb] : 0u;
    }
    unsigned s = cb[0] + cb[1] + cb[2] + cb[3];
    unsigned incl = s;
    int lane = t & 63;
#pragma unroll
    for (int off = 1; off < 64; off <<= 1) {
        unsigned u = __shfl_up(incl, off, 64);
        if (lane >= off) incl += u;
    }
    if (lane == 63) wsum[t >> 6] = incl;
    __syncthreads();
    if (t == 0) {
        unsigned a = 0;
        for (int i = 0; i < 4; ++i) { unsigned v = wsum[i]; wsum[i] = a; a += v; }
    }
    __syncthreads();
    unsigned bs = incl - s + wsum[t >> 6];
#pragma unroll
    for (int k = 0; k < 4; ++k) {
        int bb = 4 * t + k;
        if (bb < nbuk) offs[bb] = bs;
        bs += cb[k];
    }
    __syncthreads();
#pragma unroll
    for (int i = 0; i < 4; ++i)
        if (myB[i] >= 0) stage[offs[myB[i]] + myR[i]] = myPk[i];
    __syncthreads();
    if (cc == CHUNK) {
        ((uint4*)(pairsA + base))[t] = ((const uint4*)stage)[t];
    } else {
        for (int j = t; j < cc; j += 256) pairsA[base + j] = stage[j];
    }
    size_t rb = (size_t)blockIdx.x * (nbuk + 1);
    for (int i = t; i <= nbuk; i += 256)
        chk[rb + i] = (unsigned short)((i < nbuk) ? offs[i] : (unsigned)cc);
}

// ---- transpose chk[nblk][nbukR] -> chkT[nbukR][nblkP], 32x32 LDS tiles --
__global__ void __launch_bounds__(256) k_tr(const unsigned short* __restrict__ chk,
                                            unsigned short* __restrict__ chkT,
                                            int nblk, int nbukR, int nblkP) {
    __shared__ unsigned short tile[32][33];
    int r0 = blockIdx.x * 32, c0 = blockIdx.y * 32;
    int tx = threadIdx.x & 31, ty = threadIdx.x >> 5;   // 8 rows per pass
#pragma unroll
    for (int k = 0; k < 4; ++k) {
        int r = r0 + ty + k * 8, c = c0 + tx;
        if (r < nblk && c < nbukR) tile[ty + k * 8][tx] = chk[(size_t)r * nbukR + c];
    }
    __syncthreads();
#pragma unroll
    for (int k = 0; k < 4; ++k) {
        int c = c0 + ty + k * 8, r = r0 + tx;
        if (c < nbukR && r < nblk) chkT[(size_t)c * nblkP + r] = tile[tx][ty + k * 8];
    }
}

// ---- per-bucket: gather slices (coalesced metadata), sort by dst, emit --
__global__ void __launch_bounds__(512) k_sort(
        const unsigned* __restrict__ pairsA, const unsigned short* __restrict__ chkT,
        unsigned* __restrict__ pairs2, unsigned* __restrict__ offsG,
        float* __restrict__ dis, int nblk, int nblkP, int nbuk, int n) {
    __shared__ unsigned stage[CAP];
    __shared__ unsigned sorted[CAP];
    __shared__ unsigned cntN[NPB];
    __shared__ unsigned offsN[NPB];
    __shared__ unsigned cur[NPB];
    __shared__ unsigned wsum[8];
    __shared__ unsigned totS;
    int t = threadIdx.x, b = blockIdx.x;
    const unsigned short* r0 = chkT + (size_t)b * nblkP;
    const unsigned short* r1 = r0 + nblkP;

    unsigned st[4], ct[4];
#pragma unroll
    for (int k = 0; k < 4; ++k) {
        int ch = 4 * t + k;
        if (ch < nblk) {
            st[k] = r0[ch];
            ct[k] = (unsigned)r1[ch] - st[k];
        } else { st[k] = 0; ct[k] = 0; }
    }
    unsigned s = ct[0] + ct[1] + ct[2] + ct[3];
    unsigned incl = s;
    int lane = t & 63;
#pragma unroll
    for (int off = 1; off < 64; off <<= 1) {
        unsigned u = __shfl_up(incl, off, 64);
        if (lane >= off) incl += u;
    }
    if (lane == 63) wsum[t >> 6] = incl;
    __syncthreads();
    if (t == 0) {
        unsigned a = 0;
        for (int i = 0; i < 8; ++i) { unsigned v = wsum[i]; wsum[i] = a; a += v; }
        totS = a;
    }
    if (t < NPB) cntN[t] = 0;
    __syncthreads();
    unsigned bs = incl - s + wsum[t >> 6];
#pragma unroll
    for (int k = 0; k < 4; ++k) {
        if (ct[k]) {
            const unsigned* sp = pairsA + (size_t)(4 * t + k) * CHUNK + st[k];
            for (unsigned u = 0; u < ct[k]; ++u)
                if (bs + u < CAP) stage[bs + u] = sp[u];
        }
        bs += ct[k];
    }
    __syncthreads();
    int cbt = (int)min(totS, (unsigned)CAP);
    for (int i = t; i < cbt; i += 512) atomicAdd(&cntN[stage[i] >> 24], 1u);
    __syncthreads();
    if (t < NPB) {
        unsigned c = cntN[t], in2 = c;
#pragma unroll
        for (int off = 1; off < 64; off <<= 1) {
            unsigned u = __shfl_up(in2, off, 64);
            if (lane >= off) in2 += u;
        }
        if (lane == 63) wsum[t >> 6] = in2;
        offsN[t] = in2 - c;                  // wave-local exclusive (base added below)
    }
    __syncthreads();
    if (t == 0) { unsigned a = wsum[0]; wsum[0] = 0; wsum[1] = a; }
    __syncthreads();
    if (t < NPB) {
        unsigned o = offsN[t] + wsum[t >> 6];
        offsN[t] = o;
        cur[t] = o;
    }
    __syncthreads();
    for (int i = t; i < cbt; i += 512) {
        unsigned pk = stage[i];
        sorted[atomicAdd(&cur[pk >> 24], 1u)] = pk;
    }
    __syncthreads();
    int cb4 = (cbt + 3) >> 2;
    for (int i = t; i < cb4; i += 512)
        ((uint4*)(pairs2 + (size_t)b * CAP))[i] = ((const uint4*)sorted)[i];
    if (t <= NPB) offsG[(size_t)b * (NPB + 1) + t] = (t < NPB) ? offsN[t] : (unsigned)cbt;
    int nd = b * NPB + t;
    if (t < NPB && nd < n) dis[nd] = rsqrtf((float)(cntN[t] + 1));  // +1 self-loop
}

// ------- h1s = (x @ W1) * dis[node]  via bf16 MFMA, fp16 output ----------
__global__ void __launch_bounds__(256) k_gemm1(const float* __restrict__ x,
                                               const ushort* __restrict__ W1p,
                                               const float* __restrict__ dis,
                                               _Float16* __restrict__ h1s, int n) {
    int t = threadIdx.x, wave = t >> 6, lane = t & 63;
    int nb = blockIdx.x * 64 + wave * 16;
    int arow = nb + (lane & 15);            // A: row = lane&15
    int g = lane >> 4;                      // k-group
    const bf16x8* Wp = (const bf16x8*)W1p;

    f32x4 acc0 = {0.f, 0.f, 0.f, 0.f}, acc1 = acc0, acc2 = acc0, acc3 = acc0;

#pragma unroll
    for (int kc = 0; kc < 4; ++kc) {
        bf16x8 a;
        if (arow < n) {
            const float4* xp = (const float4*)(x + (size_t)arow * IN_DIM + kc * 32 + g * 8);
            float4 x0 = xp[0], x1 = xp[1];
            a[0] = f2bf(x0.x); a[1] = f2bf(x0.y); a[2] = f2bf(x0.z); a[3] = f2bf(x0.w);
            a[4] = f2bf(x1.x); a[5] = f2bf(x1.y); a[6] = f2bf(x1.z); a[7] = f2bf(x1.w);
        } else {
            for (int i = 0; i < 8; ++i) a[i] = 0;
        }
        acc0 = __builtin_amdgcn_mfma_f32_16x16x32_bf16(a, Wp[(kc * 4 + 0) * 64 + lane], acc0, 0, 0, 0);
        acc1 = __builtin_amdgcn_mfma_f32_16x16x32_bf16(a, Wp[(kc * 4 + 1) * 64 + lane], acc1, 0, 0, 0);
        acc2 = __builtin_amdgcn_mfma_f32_16x16x32_bf16(a, Wp[(kc * 4 + 2) * 64 + lane], acc2, 0, 0, 0);
        acc3 = __builtin_amdgcn_mfma_f32_16x16x32_bf16(a, Wp[(kc * 4 + 3) * 64 + lane], acc3, 0, 0, 0);
    }

    // D: col = lane&15, row = (lane>>4)*4 + reg
    int c = lane & 15, rbase = g * 4;
    float dn[4];
    int nd[4];
#pragma unroll
    for (int r = 0; r < 4; ++r) {
        nd[r] = nb + rbase + r;
        dn[r] = (nd[r] < n) ? dis[nd[r]] : 0.f;
    }
#define EPI(FB, ACC)                                                          \
    {                                                                         \
        int f = FB * 16 + c;                                                  \
        _Pragma("unroll") for (int r = 0; r < 4; ++r) {                       \
            if (nd[r] < n)                                                    \
                h1s[(size_t)nd[r] * HID + f] = (_Float16)(ACC[r] * dn[r]);    \
        }                                                                     \
    }
    EPI(0, acc0) EPI(1, acc1) EPI(2, acc2) EPI(3, acc3)
#undef EPI
}

// ---- layer-1 gather: 256 thr / 32 nodes; 2-node interleave for MLP ------
// self-loop row added AFTER the cross-group merge (once), not before.
__global__ void __launch_bounds__(256) k_gather1(
        const unsigned* __restrict__ pairs2, const unsigned* __restrict__ offsG,
        const _Float16* __restrict__ h1s, const float* __restrict__ dis,
        const float* __restrict__ b1, const float* __restrict__ W2,
        float* __restrict__ es, int n) {
    __shared__ unsigned sortedL[SLDS];
    __shared__ unsigned offsL[33];
    int t = threadIdx.x;
    int nb0 = blockIdx.x * 32;              // first node of this quarter-bucket
    int b = nb0 >> NPB_SH;
    int dl0 = nb0 & (NPB - 1);              // 0, 32, 64, 96
    if (t <= 32) offsL[t] = offsG[(size_t)b * (NPB + 1) + dl0 + t];
    __syncthreads();
    int o0 = (int)offsL[0], o1 = (int)offsL[32];
    int len = o1 - o0;
    const unsigned* gseg = pairs2 + (size_t)b * CAP;
    for (int i = t; i < len && i < SLDS; i += 256) sortedL[i] = gseg[o0 + i];
    __syncthreads();

    int wave = t >> 6, lane = t & 63;
    int grp = lane >> 4, sub = lane & 15;
    float4 bb  = *(const float4*)(b1 + sub * 4);
    float4 w01 = *(const float4*)(W2 + sub * 8);
    float4 w23 = *(const float4*)(W2 + sub * 8 + 4);

#define EPILOG(A0, A1, A2, A3, SV, ND)                                         \
    {                                                                          \
        A0 += __shfl_xor(A0, 16); A0 += __shfl_xor(A0, 32);                    \
        A1 += __shfl_xor(A1, 16); A1 += __shfl_xor(A1, 32);                    \
        A2 += __shfl_xor(A2, 16); A2 += __shfl_xor(A2, 32);                    \
        A3 += __shfl_xor(A3, 16); A3 += __shfl_xor(A3, 32);                    \
        A0 += (float)SV[0]; A1 += (float)SV[1];                                \
        A2 += (float)SV[2]; A3 += (float)SV[3];                                \
        float d = dis[ND];                                                     \
        float v0 = fast_tanh(fmaf(A0, d, bb.x));                               \
        float v1 = fast_tanh(fmaf(A1, d, bb.y));                               \
        float v2 = fast_tanh(fmaf(A2, d, bb.z));                               \
        float v3 = fast_tanh(fmaf(A3, d, bb.w));                               \
        float s0 = v0 * w01.x + v1 * w01.z + v2 * w23.x + v3 * w23.z;          \
        float s1 = v0 * w01.y + v1 * w01.w + v2 * w23.y + v3 * w23.w;          \
        s0 += __shfl_xor(s0, 1); s1 += __shfl_xor(s1, 1);                      \
        s0 += __shfl_xor(s0, 2); s1 += __shfl_xor(s1, 2);                      \
        s0 += __shfl_xor(s0, 4); s1 += __shfl_xor(s1, 4);                      \
        s0 += __shfl_xor(s0, 8); s1 += __shfl_xor(s1, 8);                      \
        if (lane == 0) {                                                       \
            es[(ND) * 2 + 0] = s0 * d;                                         \
            es[(ND) * 2 + 1] = s1 * d;                                         \
        }                                                                      \
    }

#define GBODY(FETCHA, FETCHB)                                                  \
    for (int it = 0; it < 8; it += 2) {                                        \
        int dlA = wave * 8 + it, dlB = dlA + 1;                                \
        int ndA = nb0 + dlA, ndB = nb0 + dlB;                                  \
        if (ndA >= n) break;                                                   \
        bool okB = ndB < n;                                                    \
        int pA = (int)offsL[dlA] + grp, pA1 = (int)offsL[dlA + 1];             \
        int pB = (int)offsL[dlB] + grp, pB1 = (int)offsL[dlB + 1];             \
        if (!okB) pB = pB1;                                                    \
        float a0 = 0.f, a1 = 0.f, a2 = 0.f, a3 = 0.f;                          \
        float c0 = 0.f, c1 = 0.f, c2 = 0.f, c3 = 0.f;                          \
        _Pragma("unroll 2")                                                    \
        while (pA < pA1 || pB < pB1) {                                         \
            if (pA < pA1) {                                                    \
                unsigned srcn = (FETCHA) & 0xFFFFFFu;                          \
                f16x4 v = *(const f16x4*)(h1s + (size_t)srcn * HID + sub * 4); \
                a0 += (float)v[0]; a1 += (float)v[1];                          \
                a2 += (float)v[2]; a3 += (float)v[3];                          \
                pA += 4;                                                       \
            }                                                                  \
            if (pB < pB1) {                                                    \
                unsigned srcn = (FETCHB) & 0xFFFFFFu;                          \
                f16x4 v = *(const f16x4*)(h1s + (size_t)srcn * HID + sub * 4); \
                c0 += (float)v[0]; c1 += (float)v[1];                          \
                c2 += (float)v[2]; c3 += (float)v[3];                          \
                pB += 4;                                                       \
            }                                                                  \
        }                                                                      \
        f16x4 svA = *(const f16x4*)(h1s + (size_t)ndA * HID + sub * 4);        \
        EPILOG(a0, a1, a2, a3, svA, ndA)                                       \
        if (okB) {                                                             \
            f16x4 svB = *(const f16x4*)(h1s + (size_t)ndB * HID + sub * 4);    \
            EPILOG(c0, c1, c2, c3, svB, ndB)                                   \
        }                                                                      \
    }

    if (len <= SLDS) {
        GBODY(sortedL[pA - o0], sortedL[pB - o0])
    } else {                                 // statistically impossible fallback
        GBODY(gseg[pA], gseg[pB])
    }
#undef GBODY
#undef EPILOG
}

// ---- layer-2: per-node segment walk + tanh + classifier + sigmoid ------
__global__ void __launch_bounds__(128) k_pass2b(
        const unsigned* __restrict__ pairs2, const unsigned* __restrict__ offsG,
        const float* __restrict__ es, const float* __restrict__ dis,
        const float* __restrict__ b2, const float* __restrict__ Wc,
        const float* __restrict__ bc, float* __restrict__ out, int n) {
    int t = threadIdx.x, b = blockIdx.x;
    int nd = b * NPB + t;
    if (nd >= n) return;
    const unsigned* seg = pairs2 + (size_t)b * CAP;
    int p0 = (int)offsG[(size_t)b * (NPB + 1) + t];
    int p1 = (int)offsG[(size_t)b * (NPB + 1) + t + 1];
    float2 self = *(const float2*)(es + (size_t)nd * 2);
    float a0 = self.x, a1 = self.y;
    for (int p = p0; p < p1; ++p) {
        unsigned srcn = seg[p] & 0xFFFFFFu;
        float2 v = *(const float2*)(es + (size_t)srcn * 2);
        a0 += v.x; a1 += v.y;
    }
    float d = dis[nd];
    float e0 = fast_tanh(fmaf(a0, d, b2[0]));
    float e1 = fast_tanh(fmaf(a1, d, b2[1]));
    float z = fmaf(e0, Wc[0], fmaf(e1, Wc[1], bc[0]));
    out[nd] = __builtin_amdgcn_rcpf(1.f + __expf(-z));
}

extern "C" void kernel_launch(void* const* d_in, const int* in_sizes, int n_in,
                              void* d_out, int out_size, void* d_ws, size_t ws_size,
                              hipStream_t stream) {
    const float* x  = (const float*)d_in[0];
    const int*   ei = (const int*)d_in[1];   // [2, E] as int32
    const float* W1 = (const float*)d_in[2];
    const float* b1 = (const float*)d_in[3];
    const float* W2 = (const float*)d_in[4];
    const float* b2 = (const float*)d_in[5];
    const float* Wc = (const float*)d_in[6];
    const float* bc = (const float*)d_in[7];

    const int n = in_sizes[0] / IN_DIM;
    const int E = in_sizes[1] / 2;
    const int* row = ei;
    const int* col = ei + E;
    const int nbuk = (n + NPB - 1) / NPB;        // 782 (<=1024)
    const int nbukR = nbuk + 1;
    const int nblk = (E + CHUNK - 1) / CHUNK;    // 1563 (<=2048)
    const int nblkP = (nblk + 3) & ~3;

    // workspace layout, 512B-aligned slices
    char* w = (char*)d_ws;
    auto alloc = [&](size_t bytes) {
        char* p = w;
        w += (bytes + 511) & ~(size_t)511;
        return p;
    };
    unsigned*       pairsA = (unsigned*)alloc((size_t)nblk * CHUNK * 4);
    unsigned short* chk    = (unsigned short*)alloc((size_t)nblk * nbukR * 2);
    unsigned short* chkT   = (unsigned short*)alloc((size_t)nbukR * nblkP * 2);
    unsigned*       pairs2 = (unsigned*)alloc((size_t)nbuk * CAP * 4);
    unsigned*       offsG  = (unsigned*)alloc((size_t)nbuk * (NPB + 1) * 4);
    float*          dis    = (float*)alloc((size_t)n * 4);
    ushort*         W1p    = (ushort*)alloc(16 * 64 * 8 * 2);
    _Float16*       h1s    = (_Float16*)alloc((size_t)n * HID * 2);
    float*          es     = (float*)alloc((size_t)n * 2 * 4);

    k_packW   <<<32, 256, 0, stream>>>(W1, W1p);
    k_binpairs<<<nblk, 256, 0, stream>>>(row, col, pairsA, chk, E, nbuk);
    {
        dim3 g((nblk + 31) / 32, (nbukR + 31) / 32);
        k_tr<<<g, 256, 0, stream>>>(chk, chkT, nblk, nbukR, nblkP);
    }
    k_sort    <<<nbuk, 512, 0, stream>>>(pairsA, chkT, pairs2, offsG, dis,
                                         nblk, nblkP, nbuk, n);
    k_gemm1   <<<(n + 63) / 64, 256, 0, stream>>>(x, W1p, dis, h1s, n);
    k_gather1 <<<(n + 31) / 32, 256, 0, stream>>>(pairs2, offsG, h1s, dis, b1, W2, es, n);
    k_pass2b  <<<nbuk, 128, 0, stream>>>(pairs2, offsG, es, dis, b2, Wc, bc,
                                         (float*)d_out, n);
}

// Round 15
// 110.874 us; speedup vs baseline: 1.0676x; 1.0676x over previous
//
#include <hip/hip_runtime.h>
#include <math.h>

#define IN_DIM 128
#define HID 64
#define NPB 128            // nodes per bucket
#define NPB_SH 7
#define CAP 4096           // sorted-pairs capacity per bucket (mean 2048)
#define CHUNK 1024         // edges per binning block
#define SLDS 1024          // gather1 LDS pair-stage capacity (quarter-bucket)

typedef __attribute__((ext_vector_type(8))) short bf16x8;
typedef __attribute__((ext_vector_type(4))) float f32x4;
typedef __attribute__((ext_vector_type(4))) _Float16 f16x4;

static __device__ inline short f2bf(float f) {
    unsigned u = __float_as_uint(f);
    u += 0x7fff + ((u >> 16) & 1);          // RNE
    return (short)(u >> 16);
}

// tanh via v_exp + v_rcp: ~5 VALU instrs, err ~1e-6 (vs library tanhf)
static __device__ inline float fast_tanh(float x) {
    float e = __expf(x * 2.0f);
    return 1.0f - 2.0f * __builtin_amdgcn_rcpf(e + 1.0f);
}

// ------- pack W1 [128][64] f32 -> bf16 MFMA B-fragment order -------------
__global__ void k_packW(const float* __restrict__ W1, ushort* __restrict__ W1p) {
    int idx = blockIdx.x * 256 + threadIdx.x;        // 0..8191
    int i = idx & 7, lane = (idx >> 3) & 63, fb = (idx >> 9) & 3, kc = (idx >> 11) & 3;
    int k = kc * 32 + (lane >> 4) * 8 + i;
    int f = fb * 16 + (lane & 15);
    W1p[idx] = (ushort)f2bf(W1[k * HID + f]);
}

// ---- binning: 256 thr, 1024 edges; counting-sort by bucket; coalesced ---
__global__ void __launch_bounds__(256) k_binpairs(
        const int* __restrict__ row, const int* __restrict__ col,
        unsigned* __restrict__ pairsA, unsigned short* __restrict__ chk,
        int E, int nbuk) {
    __shared__ unsigned cntL[1024];
    __shared__ unsigned offs[1024];
    __shared__ unsigned wsum[4];
    __shared__ unsigned stage[CHUNK];
    int t = threadIdx.x;
    int base = blockIdx.x * CHUNK;
    int cc = min(CHUNK, E - base);

    for (int i = t; i < nbuk; i += 256) cntL[i] = 0;
    __syncthreads();

    unsigned myPk[4], myR[4];
    int myB[4];
#pragma unroll
    for (int i = 0; i < 4; ++i) {
        int j = i * 256 + t;
        myB[i] = -1;
        if (j < cc) {
            int r = row[base + j], c = col[base + j];
            int b = c >> NPB_SH;
            myR[i] = atomicAdd(&cntL[b], 1u);
            myPk[i] = (unsigned)r | ((unsigned)(c & (NPB - 1)) << 24);
            myB[i] = b;
        }
    }
    __syncthreads();
    // exclusive scan, 4 bins per thread
    unsigned cb[4];
#pragma unroll
    for (int k = 0; k < 4; ++k) {
        int bb = 4 * t + k;
        cb[k] = (bb < nbuk) ? cntL[bb] : 0u;
    }
    unsigned s = cb[0] + cb[1] + cb[2] + cb[3];
    unsigned incl = s;
    int lane = t & 63;
#pragma unroll
    for (int off = 1; off < 64; off <<= 1) {
        unsigned u = __shfl_up(incl, off, 64);
        if (lane >= off) incl += u;
    }
    if (lane == 63) wsum[t >> 6] = incl;
    __syncthreads();
    if (t == 0) {
        unsigned a = 0;
        for (int i = 0; i < 4; ++i) { unsigned v = wsum[i]; wsum[i] = a; a += v; }
    }
    __syncthreads();
    unsigned bs = incl - s + wsum[t >> 6];
#pragma unroll
    for (int k = 0; k < 4; ++k) {
        int bb = 4 * t + k;
        if (bb < nbuk) offs[bb] = bs;
        bs += cb[k];
    }
    __syncthreads();
#pragma unroll
    for (int i = 0; i < 4; ++i)
        if (myB[i] >= 0) stage[offs[myB[i]] + myR[i]] = myPk[i];
    __syncthreads();
    if (cc == CHUNK) {
        ((uint4*)(pairsA + base))[t] = ((const uint4*)stage)[t];
    } else {
        for (int j = t; j < cc; j += 256) pairsA[base + j] = stage[j];
    }
    size_t rb = (size_t)blockIdx.x * (nbuk + 1);
    for (int i = t; i <= nbuk; i += 256)
        chk[rb + i] = (unsigned short)((i < nbuk) ? offs[i] : (unsigned)cc);
}

// ---- transpose chk[nblk][nbukR] -> chkT[nbukR][nblkP], 32x32 LDS tiles --
__global__ void __launch_bounds__(256) k_tr(const unsigned short* __restrict__ chk,
                                            unsigned short* __restrict__ chkT,
                                            int nblk, int nbukR, int nblkP) {
    __shared__ unsigned short tile[32][33];
    int r0 = blockIdx.x * 32, c0 = blockIdx.y * 32;
    int tx = threadIdx.x & 31, ty = threadIdx.x >> 5;   // 8 rows per pass
#pragma unroll
    for (int k = 0; k < 4; ++k) {
        int r = r0 + ty + k * 8, c = c0 + tx;
        if (r < nblk && c < nbukR) tile[ty + k * 8][tx] = chk[(size_t)r * nbukR + c];
    }
    __syncthreads();
#pragma unroll
    for (int k = 0; k < 4; ++k) {
        int c = c0 + ty + k * 8, r = r0 + tx;
        if (c < nbukR && r < nblk) chkT[(size_t)c * nblkP + r] = tile[tx][ty + k * 8];
    }
}

// ---- per-bucket: gather slices (coalesced metadata), sort by dst, emit --
__global__ void __launch_bounds__(512) k_sort(
        const unsigned* __restrict__ pairsA, const unsigned short* __restrict__ chkT,
        unsigned* __restrict__ pairs2, unsigned* __restrict__ offsG,
        float* __restrict__ dis, int nblk, int nblkP, int nbuk, int n) {
    __shared__ unsigned stage[CAP];
    __shared__ unsigned sorted[CAP];
    __shared__ unsigned cntN[NPB];
    __shared__ unsigned offsN[NPB];
    __shared__ unsigned cur[NPB];
    __shared__ unsigned wsum[8];
    __shared__ unsigned totS;
    int t = threadIdx.x, b = blockIdx.x;
    const unsigned short* r0 = chkT + (size_t)b * nblkP;
    const unsigned short* r1 = r0 + nblkP;

    unsigned st[4], ct[4];
#pragma unroll
    for (int k = 0; k < 4; ++k) {
        int ch = 4 * t + k;
        if (ch < nblk) {
            st[k] = r0[ch];
            ct[k] = (unsigned)r1[ch] - st[k];
        } else { st[k] = 0; ct[k] = 0; }
    }
    unsigned s = ct[0] + ct[1] + ct[2] + ct[3];
    unsigned incl = s;
    int lane = t & 63;
#pragma unroll
    for (int off = 1; off < 64; off <<= 1) {
        unsigned u = __shfl_up(incl, off, 64);
        if (lane >= off) incl += u;
    }
    if (lane == 63) wsum[t >> 6] = incl;
    __syncthreads();
    if (t == 0) {
        unsigned a = 0;
        for (int i = 0; i < 8; ++i) { unsigned v = wsum[i]; wsum[i] = a; a += v; }
        totS = a;
    }
    if (t < NPB) cntN[t] = 0;
    __syncthreads();
    unsigned bs = incl - s + wsum[t >> 6];
#pragma unroll
    for (int k = 0; k < 4; ++k) {
        if (ct[k]) {
            const unsigned* sp = pairsA + (size_t)(4 * t + k) * CHUNK + st[k];
            for (unsigned u = 0; u < ct[k]; ++u)
                if (bs + u < CAP) stage[bs + u] = sp[u];
        }
        bs += ct[k];
    }
    __syncthreads();
    int cbt = (int)min(totS, (unsigned)CAP);
    for (int i = t; i < cbt; i += 512) atomicAdd(&cntN[stage[i] >> 24], 1u);
    __syncthreads();
    if (t < NPB) {
        unsigned c = cntN[t], in2 = c;
#pragma unroll
        for (int off = 1; off < 64; off <<= 1) {
            unsigned u = __shfl_up(in2, off, 64);
            if (lane >= off) in2 += u;
        }
        if (lane == 63) wsum[t >> 6] = in2;
        offsN[t] = in2 - c;                  // wave-local exclusive (base added below)
    }
    __syncthreads();
    if (t == 0) { unsigned a = wsum[0]; wsum[0] = 0; wsum[1] = a; }
    __syncthreads();
    if (t < NPB) {
        unsigned o = offsN[t] + wsum[t >> 6];
        offsN[t] = o;
        cur[t] = o;
    }
    __syncthreads();
    for (int i = t; i < cbt; i += 512) {
        unsigned pk = stage[i];
        sorted[atomicAdd(&cur[pk >> 24], 1u)] = pk;
    }
    __syncthreads();
    int cb4 = (cbt + 3) >> 2;
    for (int i = t; i < cb4; i += 512)
        ((uint4*)(pairs2 + (size_t)b * CAP))[i] = ((const uint4*)sorted)[i];
    if (t <= NPB) offsG[(size_t)b * (NPB + 1) + t] = (t < NPB) ? offsN[t] : (unsigned)cbt;
    int nd = b * NPB + t;
    if (t < NPB && nd < n) dis[nd] = rsqrtf((float)(cntN[t] + 1));  // +1 self-loop
}

// ------- h1s = (x @ W1) * dis[node]  via bf16 MFMA, fp16 output ----------
__global__ void __launch_bounds__(256) k_gemm1(const float* __restrict__ x,
                                               const ushort* __restrict__ W1p,
                                               const float* __restrict__ dis,
                                               _Float16* __restrict__ h1s, int n) {
    int t = threadIdx.x, wave = t >> 6, lane = t & 63;
    int nb = blockIdx.x * 64 + wave * 16;
    int arow = nb + (lane & 15);            // A: row = lane&15
    int g = lane >> 4;                      // k-group
    const bf16x8* Wp = (const bf16x8*)W1p;

    f32x4 acc0 = {0.f, 0.f, 0.f, 0.f}, acc1 = acc0, acc2 = acc0, acc3 = acc0;

#pragma unroll
    for (int kc = 0; kc < 4; ++kc) {
        bf16x8 a;
        if (arow < n) {
            const float4* xp = (const float4*)(x + (size_t)arow * IN_DIM + kc * 32 + g * 8);
            float4 x0 = xp[0], x1 = xp[1];
            a[0] = f2bf(x0.x); a[1] = f2bf(x0.y); a[2] = f2bf(x0.z); a[3] = f2bf(x0.w);
            a[4] = f2bf(x1.x); a[5] = f2bf(x1.y); a[6] = f2bf(x1.z); a[7] = f2bf(x1.w);
        } else {
            for (int i = 0; i < 8; ++i) a[i] = 0;
        }
        acc0 = __builtin_amdgcn_mfma_f32_16x16x32_bf16(a, Wp[(kc * 4 + 0) * 64 + lane], acc0, 0, 0, 0);
        acc1 = __builtin_amdgcn_mfma_f32_16x16x32_bf16(a, Wp[(kc * 4 + 1) * 64 + lane], acc1, 0, 0, 0);
        acc2 = __builtin_amdgcn_mfma_f32_16x16x32_bf16(a, Wp[(kc * 4 + 2) * 64 + lane], acc2, 0, 0, 0);
        acc3 = __builtin_amdgcn_mfma_f32_16x16x32_bf16(a, Wp[(kc * 4 + 3) * 64 + lane], acc3, 0, 0, 0);
    }

    // D: col = lane&15, row = (lane>>4)*4 + reg
    int c = lane & 15, rbase = g * 4;
    float dn[4];
    int nd[4];
#pragma unroll
    for (int r = 0; r < 4; ++r) {
        nd[r] = nb + rbase + r;
        dn[r] = (nd[r] < n) ? dis[nd[r]] : 0.f;
    }
#define EPI(FB, ACC)                                                          \
    {                                                                         \
        int f = FB * 16 + c;                                                  \
        _Pragma("unroll") for (int r = 0; r < 4; ++r) {                       \
            if (nd[r] < n)                                                    \
                h1s[(size_t)nd[r] * HID + f] = (_Float16)(ACC[r] * dn[r]);    \
        }                                                                     \
    }
    EPI(0, acc0) EPI(1, acc1) EPI(2, acc2) EPI(3, acc3)
#undef EPI
}

// ---- layer-1 gather: 256 thr / 32 nodes; R11 loop + fast_tanh epilogue --
__global__ void __launch_bounds__(256) k_gather1(
        const unsigned* __restrict__ pairs2, const unsigned* __restrict__ offsG,
        const _Float16* __restrict__ h1s, const float* __restrict__ dis,
        const float* __restrict__ b1, const float* __restrict__ W2,
        float* __restrict__ es, int n) {
    __shared__ unsigned sortedL[SLDS];
    __shared__ unsigned offsL[33];
    int t = threadIdx.x;
    int nb0 = blockIdx.x * 32;              // first node of this quarter-bucket
    int b = nb0 >> NPB_SH;
    int dl0 = nb0 & (NPB - 1);              // 0, 32, 64, 96
    if (t <= 32) offsL[t] = offsG[(size_t)b * (NPB + 1) + dl0 + t];
    __syncthreads();
    int o0 = (int)offsL[0], o1 = (int)offsL[32];
    int len = o1 - o0;
    const unsigned* gseg = pairs2 + (size_t)b * CAP;
    for (int i = t; i < len && i < SLDS; i += 256) sortedL[i] = gseg[o0 + i];
    __syncthreads();

    int wave = t >> 6, lane = t & 63;
    int grp = lane >> 4, sub = lane & 15;
    float4 bb  = *(const float4*)(b1 + sub * 4);
    float4 w01 = *(const float4*)(W2 + sub * 8);
    float4 w23 = *(const float4*)(W2 + sub * 8 + 4);

#define GBODY(FETCH)                                                           \
    for (int it = 0; it < 8; ++it) {                                           \
        int dl = wave * 8 + it;                                                \
        int nd = nb0 + dl;                                                     \
        if (nd >= n) break;                                                    \
        int p0 = (int)offsL[dl] + grp, p1 = (int)offsL[dl + 1];                \
        float a0 = 0.f, a1 = 0.f, a2 = 0.f, a3 = 0.f;                          \
        _Pragma("unroll 2")                                                    \
        for (int p = p0; p < p1; p += 4) {                                     \
            unsigned srcn = (FETCH) & 0xFFFFFFu;                               \
            f16x4 v = *(const f16x4*)(h1s + (size_t)srcn * HID + sub * 4);     \
            a0 += (float)v[0]; a1 += (float)v[1];                              \
            a2 += (float)v[2]; a3 += (float)v[3];                              \
        }                                                                      \
        a0 += __shfl_xor(a0, 16); a0 += __shfl_xor(a0, 32);                    \
        a1 += __shfl_xor(a1, 16); a1 += __shfl_xor(a1, 32);                    \
        a2 += __shfl_xor(a2, 16); a2 += __shfl_xor(a2, 32);                    \
        a3 += __shfl_xor(a3, 16); a3 += __shfl_xor(a3, 32);                    \
        f16x4 sv = *(const f16x4*)(h1s + (size_t)nd * HID + sub * 4);          \
        a0 += (float)sv[0]; a1 += (float)sv[1];                                \
        a2 += (float)sv[2]; a3 += (float)sv[3];                                \
        float d = dis[nd];                                                     \
        float v0 = fast_tanh(fmaf(a0, d, bb.x));                               \
        float v1 = fast_tanh(fmaf(a1, d, bb.y));                               \
        float v2 = fast_tanh(fmaf(a2, d, bb.z));                               \
        float v3 = fast_tanh(fmaf(a3, d, bb.w));                               \
        float s0 = v0 * w01.x + v1 * w01.z + v2 * w23.x + v3 * w23.z;          \
        float s1 = v0 * w01.y + v1 * w01.w + v2 * w23.y + v3 * w23.w;          \
        s0 += __shfl_xor(s0, 1); s1 += __shfl_xor(s1, 1);                      \
        s0 += __shfl_xor(s0, 2); s1 += __shfl_xor(s1, 2);                      \
        s0 += __shfl_xor(s0, 4); s1 += __shfl_xor(s1, 4);                      \
        s0 += __shfl_xor(s0, 8); s1 += __shfl_xor(s1, 8);                      \
        if (lane == 0) {                                                       \
            es[nd * 2 + 0] = s0 * d;                                           \
            es[nd * 2 + 1] = s1 * d;                                           \
        }                                                                      \
    }

    if (len <= SLDS) {
        GBODY(sortedL[p - o0])
    } else {                                 // statistically impossible fallback
        GBODY(gseg[p])
    }
#undef GBODY
}

// ---- layer-2: per-node segment walk + tanh + classifier + sigmoid ------
__global__ void __launch_bounds__(128) k_pass2b(
        const unsigned* __restrict__ pairs2, const unsigned* __restrict__ offsG,
        const float* __restrict__ es, const float* __restrict__ dis,
        const float* __restrict__ b2, const float* __restrict__ Wc,
        const float* __restrict__ bc, float* __restrict__ out, int n) {
    int t = threadIdx.x, b = blockIdx.x;
    int nd = b * NPB + t;
    if (nd >= n) return;
    const unsigned* seg = pairs2 + (size_t)b * CAP;
    int p0 = (int)offsG[(size_t)b * (NPB + 1) + t];
    int p1 = (int)offsG[(size_t)b * (NPB + 1) + t + 1];
    float2 self = *(const float2*)(es + (size_t)nd * 2);
    float a0 = self.x, a1 = self.y;
    for (int p = p0; p < p1; ++p) {
        unsigned srcn = seg[p] & 0xFFFFFFu;
        float2 v = *(const float2*)(es + (size_t)srcn * 2);
        a0 += v.x; a1 += v.y;
    }
    float d = dis[nd];
    float e0 = fast_tanh(fmaf(a0, d, b2[0]));
    float e1 = fast_tanh(fmaf(a1, d, b2[1]));
    float z = fmaf(e0, Wc[0], fmaf(e1, Wc[1], bc[0]));
    out[nd] = __builtin_amdgcn_rcpf(1.f + __expf(-z));
}

extern "C" void kernel_launch(void* const* d_in, const int* in_sizes, int n_in,
                              void* d_out, int out_size, void* d_ws, size_t ws_size,
                              hipStream_t stream) {
    const float* x  = (const float*)d_in[0];
    const int*   ei = (const int*)d_in[1];   // [2, E] as int32
    const float* W1 = (const float*)d_in[2];
    const float* b1 = (const float*)d_in[3];
    const float* W2 = (const float*)d_in[4];
    const float* b2 = (const float*)d_in[5];
    const float* Wc = (const float*)d_in[6];
    const float* bc = (const float*)d_in[7];

    const int n = in_sizes[0] / IN_DIM;
    const int E = in_sizes[1] / 2;
    const int* row = ei;
    const int* col = ei + E;
    const int nbuk = (n + NPB - 1) / NPB;        // 782 (<=1024)
    const int nbukR = nbuk + 1;
    const int nblk = (E + CHUNK - 1) / CHUNK;    // 1563 (<=2048)
    const int nblkP = (nblk + 3) & ~3;

    // workspace layout, 512B-aligned slices
    char* w = (char*)d_ws;
    auto alloc = [&](size_t bytes) {
        char* p = w;
        w += (bytes + 511) & ~(size_t)511;
        return p;
    };
    unsigned*       pairsA = (unsigned*)alloc((size_t)nblk * CHUNK * 4);
    unsigned short* chk    = (unsigned short*)alloc((size_t)nblk * nbukR * 2);
    unsigned short* chkT   = (unsigned short*)alloc((size_t)nbukR * nblkP * 2);
    unsigned*       pairs2 = (unsigned*)alloc((size_t)nbuk * CAP * 4);
    unsigned*       offsG  = (unsigned*)alloc((size_t)nbuk * (NPB + 1) * 4);
    float*          dis    = (float*)alloc((size_t)n * 4);
    ushort*         W1p    = (ushort*)alloc(16 * 64 * 8 * 2);
    _Float16*       h1s    = (_Float16*)alloc((size_t)n * HID * 2);
    float*          es     = (float*)alloc((size_t)n * 2 * 4);

    k_packW   <<<32, 256, 0, stream>>>(W1, W1p);
    k_binpairs<<<nblk, 256, 0, stream>>>(row, col, pairsA, chk, E, nbuk);
    {
        dim3 g((nblk + 31) / 32, (nbukR + 31) / 32);
        k_tr<<<g, 256, 0, stream>>>(chk, chkT, nblk, nbukR, nblkP);
    }
    k_sort    <<<nbuk, 512, 0, stream>>>(pairsA, chkT, pairs2, offsG, dis,
                                         nblk, nblkP, nbuk, n);
    k_gemm1   <<<(n + 63) / 64, 256, 0, stream>>>(x, W1p, dis, h1s, n);
    k_gather1 <<<(n + 31) / 32, 256, 0, stream>>>(pairs2, offsG, h1s, dis, b1, W2, es, n);
    k_pass2b  <<<nbuk, 128, 0, stream>>>(pairs2, offsG, es, dis, b2, Wc, bc,
                                         (float*)d_out, n);
}

// Round 16
// 106.384 us; speedup vs baseline: 1.1127x; 1.0422x over previous
//
#include <hip/hip_runtime.h>
#include <math.h>

#define IN_DIM 128
#define HID 64
#define NPB 128            // nodes per bucket
#define NPB_SH 7
#define CAP 4096           // sorted-pairs capacity per bucket (mean 2048)
#define CHUNK 2048         // edges per binning block (512 thr x 4)
#define SLDS 1024          // gather1 LDS pair-stage capacity (quarter-bucket)

typedef __attribute__((ext_vector_type(8))) short bf16x8;
typedef __attribute__((ext_vector_type(4))) float f32x4;
typedef __attribute__((ext_vector_type(4))) _Float16 f16x4;

static __device__ inline short f2bf(float f) {
    unsigned u = __float_as_uint(f);
    u += 0x7fff + ((u >> 16) & 1);          // RNE
    return (short)(u >> 16);
}

// tanh via v_exp + v_rcp: ~5 VALU instrs, err ~1e-6 (vs library tanhf)
static __device__ inline float fast_tanh(float x) {
    float e = __expf(x * 2.0f);
    return 1.0f - 2.0f * __builtin_amdgcn_rcpf(e + 1.0f);
}

// ------- pack W1 [128][64] f32 -> bf16 MFMA B-fragment order -------------
__global__ void k_packW(const float* __restrict__ W1, ushort* __restrict__ W1p) {
    int idx = blockIdx.x * 256 + threadIdx.x;        // 0..8191
    int i = idx & 7, lane = (idx >> 3) & 63, fb = (idx >> 9) & 3, kc = (idx >> 11) & 3;
    int k = kc * 32 + (lane >> 4) * 8 + i;
    int f = fb * 16 + (lane & 15);
    W1p[idx] = (ushort)f2bf(W1[k * HID + f]);
}

// ---- binning: 512 thr, 2048 edges; counting-sort by bucket; coalesced ---
__global__ void __launch_bounds__(512) k_binpairs(
        const int* __restrict__ row, const int* __restrict__ col,
        unsigned* __restrict__ pairsA, unsigned short* __restrict__ chk,
        int E, int nbuk) {
    __shared__ unsigned cntL[1024];
    __shared__ unsigned offs[1024];
    __shared__ unsigned wsum[8];
    __shared__ unsigned stage[CHUNK];
    int t = threadIdx.x;
    int base = blockIdx.x * CHUNK;
    int cc = min(CHUNK, E - base);

    for (int i = t; i < nbuk; i += 512) cntL[i] = 0;
    __syncthreads();

    unsigned myPk[4], myR[4];
    int myB[4];
#pragma unroll
    for (int i = 0; i < 4; ++i) {
        int j = i * 512 + t;
        myB[i] = -1;
        if (j < cc) {
            int r = row[base + j], c = col[base + j];
            int b = c >> NPB_SH;
            myR[i] = atomicAdd(&cntL[b], 1u);
            myPk[i] = (unsigned)r | ((unsigned)(c & (NPB - 1)) << 24);
            myB[i] = b;
        }
    }
    __syncthreads();
    // exclusive scan, 2 bins per thread
    unsigned cb[2];
#pragma unroll
    for (int k = 0; k < 2; ++k) {
        int bb = 2 * t + k;
        cb[k] = (bb < nbuk) ? cntL[bb] : 0u;
    }
    unsigned s = cb[0] + cb[1];
    unsigned incl = s;
    int lane = t & 63;
#pragma unroll
    for (int off = 1; off < 64; off <<= 1) {
        unsigned u = __shfl_up(incl, off, 64);
        if (lane >= off) incl += u;
    }
    if (lane == 63) wsum[t >> 6] = incl;
    __syncthreads();
    if (t == 0) {
        unsigned a = 0;
        for (int i = 0; i < 8; ++i) { unsigned v = wsum[i]; wsum[i] = a; a += v; }
    }
    __syncthreads();
    unsigned bs = incl - s + wsum[t >> 6];
#pragma unroll
    for (int k = 0; k < 2; ++k) {
        int bb = 2 * t + k;
        if (bb < nbuk) offs[bb] = bs;
        bs += cb[k];
    }
    __syncthreads();
#pragma unroll
    for (int i = 0; i < 4; ++i)
        if (myB[i] >= 0) stage[offs[myB[i]] + myR[i]] = myPk[i];
    __syncthreads();
    if (cc == CHUNK) {
        ((uint4*)(pairsA + base))[t] = ((const uint4*)stage)[t];
    } else {
        for (int j = t; j < cc; j += 512) pairsA[base + j] = stage[j];
    }
    size_t rb = (size_t)blockIdx.x * (nbuk + 1);
    for (int i = t; i <= nbuk; i += 512)
        chk[rb + i] = (unsigned short)((i < nbuk) ? offs[i] : (unsigned)cc);
}

// ---- transpose chk[nblk][nbukR] -> chkT[nbukR][nblkP], 32x32 LDS tiles --
__global__ void __launch_bounds__(256) k_tr(const unsigned short* __restrict__ chk,
                                            unsigned short* __restrict__ chkT,
                                            int nblk, int nbukR, int nblkP) {
    __shared__ unsigned short tile[32][33];
    int r0 = blockIdx.x * 32, c0 = blockIdx.y * 32;
    int tx = threadIdx.x & 31, ty = threadIdx.x >> 5;   // 8 rows per pass
#pragma unroll
    for (int k = 0; k < 4; ++k) {
        int r = r0 + ty + k * 8, c = c0 + tx;
        if (r < nblk && c < nbukR) tile[ty + k * 8][tx] = chk[(size_t)r * nbukR + c];
    }
    __syncthreads();
#pragma unroll
    for (int k = 0; k < 4; ++k) {
        int c = c0 + ty + k * 8, r = r0 + tx;
        if (c < nbukR && r < nblk) chkT[(size_t)c * nblkP + r] = tile[tx][ty + k * 8];
    }
}

// ---- per-bucket: gather slices (coalesced metadata), sort by dst, emit --
__global__ void __launch_bounds__(512) k_sort(
        const unsigned* __restrict__ pairsA, const unsigned short* __restrict__ chkT,
        unsigned* __restrict__ pairs2, unsigned* __restrict__ offsG,
        float* __restrict__ dis, int nblk, int nblkP, int nbuk, int n) {
    __shared__ unsigned stage[CAP];
    __shared__ unsigned sorted[CAP];
    __shared__ unsigned cntN[NPB];
    __shared__ unsigned offsN[NPB];
    __shared__ unsigned cur[NPB];
    __shared__ unsigned wsum[8];
    __shared__ unsigned totS;
    int t = threadIdx.x, b = blockIdx.x;
    const unsigned short* r0 = chkT + (size_t)b * nblkP;
    const unsigned short* r1 = r0 + nblkP;

    unsigned st[2], ct[2];
#pragma unroll
    for (int k = 0; k < 2; ++k) {
        int ch = 2 * t + k;
        if (ch < nblk) {
            st[k] = r0[ch];
            ct[k] = (unsigned)r1[ch] - st[k];
        } else { st[k] = 0; ct[k] = 0; }
    }
    unsigned s = ct[0] + ct[1];
    unsigned incl = s;
    int lane = t & 63;
#pragma unroll
    for (int off = 1; off < 64; off <<= 1) {
        unsigned u = __shfl_up(incl, off, 64);
        if (lane >= off) incl += u;
    }
    if (lane == 63) wsum[t >> 6] = incl;
    __syncthreads();
    if (t == 0) {
        unsigned a = 0;
        for (int i = 0; i < 8; ++i) { unsigned v = wsum[i]; wsum[i] = a; a += v; }
        totS = a;
    }
    if (t < NPB) cntN[t] = 0;
    __syncthreads();
    unsigned bs = incl - s + wsum[t >> 6];
#pragma unroll
    for (int k = 0; k < 2; ++k) {
        if (ct[k]) {
            const unsigned* sp = pairsA + (size_t)(2 * t + k) * CHUNK + st[k];
            for (unsigned u = 0; u < ct[k]; ++u)
                if (bs + u < CAP) stage[bs + u] = sp[u];
        }
        bs += ct[k];
    }
    __syncthreads();
    int cbt = (int)min(totS, (unsigned)CAP);
    for (int i = t; i < cbt; i += 512) atomicAdd(&cntN[stage[i] >> 24], 1u);
    __syncthreads();
    if (t < NPB) {
        unsigned c = cntN[t], in2 = c;
#pragma unroll
        for (int off = 1; off < 64; off <<= 1) {
            unsigned u = __shfl_up(in2, off, 64);
            if (lane >= off) in2 += u;
        }
        if (lane == 63) wsum[t >> 6] = in2;
        offsN[t] = in2 - c;                  // wave-local exclusive (base added below)
    }
    __syncthreads();
    if (t == 0) { unsigned a = wsum[0]; wsum[0] = 0; wsum[1] = a; }
    __syncthreads();
    if (t < NPB) {
        unsigned o = offsN[t] + wsum[t >> 6];
        offsN[t] = o;
        cur[t] = o;
    }
    __syncthreads();
    for (int i = t; i < cbt; i += 512) {
        unsigned pk = stage[i];
        sorted[atomicAdd(&cur[pk >> 24], 1u)] = pk;
    }
    __syncthreads();
    int cb4 = (cbt + 3) >> 2;
    for (int i = t; i < cb4; i += 512)
        ((uint4*)(pairs2 + (size_t)b * CAP))[i] = ((const uint4*)sorted)[i];
    if (t <= NPB) offsG[(size_t)b * (NPB + 1) + t] = (t < NPB) ? offsN[t] : (unsigned)cbt;
    int nd = b * NPB + t;
    if (t < NPB && nd < n) dis[nd] = rsqrtf((float)(cntN[t] + 1));  // +1 self-loop
}

// ------- h1s = (x @ W1) * dis[node]  via bf16 MFMA, fp16 output ----------
__global__ void __launch_bounds__(256) k_gemm1(const float* __restrict__ x,
                                               const ushort* __restrict__ W1p,
                                               const float* __restrict__ dis,
                                               _Float16* __restrict__ h1s, int n) {
    int t = threadIdx.x, wave = t >> 6, lane = t & 63;
    int nb = blockIdx.x * 64 + wave * 16;
    int arow = nb + (lane & 15);            // A: row = lane&15
    int g = lane >> 4;                      // k-group
    const bf16x8* Wp = (const bf16x8*)W1p;

    f32x4 acc0 = {0.f, 0.f, 0.f, 0.f}, acc1 = acc0, acc2 = acc0, acc3 = acc0;

#pragma unroll
    for (int kc = 0; kc < 4; ++kc) {
        bf16x8 a;
        if (arow < n) {
            const float4* xp = (const float4*)(x + (size_t)arow * IN_DIM + kc * 32 + g * 8);
            float4 x0 = xp[0], x1 = xp[1];
            a[0] = f2bf(x0.x); a[1] = f2bf(x0.y); a[2] = f2bf(x0.z); a[3] = f2bf(x0.w);
            a[4] = f2bf(x1.x); a[5] = f2bf(x1.y); a[6] = f2bf(x1.z); a[7] = f2bf(x1.w);
        } else {
            for (int i = 0; i < 8; ++i) a[i] = 0;
        }
        acc0 = __builtin_amdgcn_mfma_f32_16x16x32_bf16(a, Wp[(kc * 4 + 0) * 64 + lane], acc0, 0, 0, 0);
        acc1 = __builtin_amdgcn_mfma_f32_16x16x32_bf16(a, Wp[(kc * 4 + 1) * 64 + lane], acc1, 0, 0, 0);
        acc2 = __builtin_amdgcn_mfma_f32_16x16x32_bf16(a, Wp[(kc * 4 + 2) * 64 + lane], acc2, 0, 0, 0);
        acc3 = __builtin_amdgcn_mfma_f32_16x16x32_bf16(a, Wp[(kc * 4 + 3) * 64 + lane], acc3, 0, 0, 0);
    }

    // D: col = lane&15, row = (lane>>4)*4 + reg
    int c = lane & 15, rbase = g * 4;
    float dn[4];
    int nd[4];
#pragma unroll
    for (int r = 0; r < 4; ++r) {
        nd[r] = nb + rbase + r;
        dn[r] = (nd[r] < n) ? dis[nd[r]] : 0.f;
    }
#define EPI(FB, ACC)                                                          \
    {                                                                         \
        int f = FB * 16 + c;                                                  \
        _Pragma("unroll") for (int r = 0; r < 4; ++r) {                       \
            if (nd[r] < n)                                                    \
                h1s[(size_t)nd[r] * HID + f] = (_Float16)(ACC[r] * dn[r]);    \
        }                                                                     \
    }
    EPI(0, acc0) EPI(1, acc1) EPI(2, acc2) EPI(3, acc3)
#undef EPI
}

// ---- layer-1 gather: 256 thr / 32 nodes; R11 loop + fast_tanh epilogue --
__global__ void __launch_bounds__(256) k_gather1(
        const unsigned* __restrict__ pairs2, const unsigned* __restrict__ offsG,
        const _Float16* __restrict__ h1s, const float* __restrict__ dis,
        const float* __restrict__ b1, const float* __restrict__ W2,
        float* __restrict__ es, int n) {
    __shared__ unsigned sortedL[SLDS];
    __shared__ unsigned offsL[33];
    int t = threadIdx.x;
    int nb0 = blockIdx.x * 32;              // first node of this quarter-bucket
    int b = nb0 >> NPB_SH;
    int dl0 = nb0 & (NPB - 1);              // 0, 32, 64, 96
    if (t <= 32) offsL[t] = offsG[(size_t)b * (NPB + 1) + dl0 + t];
    __syncthreads();
    int o0 = (int)offsL[0], o1 = (int)offsL[32];
    int len = o1 - o0;
    const unsigned* gseg = pairs2 + (size_t)b * CAP;
    for (int i = t; i < len && i < SLDS; i += 256) sortedL[i] = gseg[o0 + i];
    __syncthreads();

    int wave = t >> 6, lane = t & 63;
    int grp = lane >> 4, sub = lane & 15;
    float4 bb  = *(const float4*)(b1 + sub * 4);
    float4 w01 = *(const float4*)(W2 + sub * 8);
    float4 w23 = *(const float4*)(W2 + sub * 8 + 4);

#define GBODY(FETCH)                                                           \
    for (int it = 0; it < 8; ++it) {                                           \
        int dl = wave * 8 + it;                                                \
        int nd = nb0 + dl;                                                     \
        if (nd >= n) break;                                                    \
        int p0 = (int)offsL[dl] + grp, p1 = (int)offsL[dl + 1];                \
        float a0 = 0.f, a1 = 0.f, a2 = 0.f, a3 = 0.f;                          \
        _Pragma("unroll 2")                                                    \
        for (int p = p0; p < p1; p += 4) {                                     \
            unsigned srcn = (FETCH) & 0xFFFFFFu;                               \
            f16x4 v = *(const f16x4*)(h1s + (size_t)srcn * HID + sub * 4);     \
            a0 += (float)v[0]; a1 += (float)v[1];                              \
            a2 += (float)v[2]; a3 += (float)v[3];                              \
        }                                                                      \
        a0 += __shfl_xor(a0, 16); a0 += __shfl_xor(a0, 32);                    \
        a1 += __shfl_xor(a1, 16); a1 += __shfl_xor(a1, 32);                    \
        a2 += __shfl_xor(a2, 16); a2 += __shfl_xor(a2, 32);                    \
        a3 += __shfl_xor(a3, 16); a3 += __shfl_xor(a3, 32);                    \
        f16x4 sv = *(const f16x4*)(h1s + (size_t)nd * HID + sub * 4);          \
        a0 += (float)sv[0]; a1 += (float)sv[1];                                \
        a2 += (float)sv[2]; a3 += (float)sv[3];                                \
        float d = dis[nd];                                                     \
        float v0 = fast_tanh(fmaf(a0, d, bb.x));                               \
        float v1 = fast_tanh(fmaf(a1, d, bb.y));                               \
        float v2 = fast_tanh(fmaf(a2, d, bb.z));                               \
        float v3 = fast_tanh(fmaf(a3, d, bb.w));                               \
        float s0 = v0 * w01.x + v1 * w01.z + v2 * w23.x + v3 * w23.z;          \
        float s1 = v0 * w01.y + v1 * w01.w + v2 * w23.y + v3 * w23.w;          \
        s0 += __shfl_xor(s0, 1); s1 += __shfl_xor(s1, 1);                      \
        s0 += __shfl_xor(s0, 2); s1 += __shfl_xor(s1, 2);                      \
        s0 += __shfl_xor(s0, 4); s1 += __shfl_xor(s1, 4);                      \
        s0 += __shfl_xor(s0, 8); s1 += __shfl_xor(s1, 8);                      \
        if (lane == 0) {                                                       \
            es[nd * 2 + 0] = s0 * d;                                           \
            es[nd * 2 + 1] = s1 * d;                                           \
        }                                                                      \
    }

    if (len <= SLDS) {
        GBODY(sortedL[p - o0])
    } else {                                 // statistically impossible fallback
        GBODY(gseg[p])
    }
#undef GBODY
}

// ---- layer-2: 4 lanes per node walk edges; quad-shfl merge; epilogue ----
__global__ void __launch_bounds__(512) k_pass2b(
        const unsigned* __restrict__ pairs2, const unsigned* __restrict__ offsG,
        const float* __restrict__ es, const float* __restrict__ dis,
        const float* __restrict__ b2, const float* __restrict__ Wc,
        const float* __restrict__ bc, float* __restrict__ out, int n) {
    int t = threadIdx.x, b = blockIdx.x;
    int node = t >> 2, q = t & 3;
    int nd = b * NPB + node;
    if (nd >= n) return;
    const unsigned* seg = pairs2 + (size_t)b * CAP;
    int p0 = (int)offsG[(size_t)b * (NPB + 1) + node];
    int p1 = (int)offsG[(size_t)b * (NPB + 1) + node + 1];
    float a0 = 0.f, a1 = 0.f;
    if (q == 0) {
        float2 self = *(const float2*)(es + (size_t)nd * 2);
        a0 = self.x; a1 = self.y;
    }
    for (int p = p0 + q; p < p1; p += 4) {
        unsigned srcn = seg[p] & 0xFFFFFFu;
        float2 v = *(const float2*)(es + (size_t)srcn * 2);
        a0 += v.x; a1 += v.y;
    }
    a0 += __shfl_xor(a0, 1); a1 += __shfl_xor(a1, 1);
    a0 += __shfl_xor(a0, 2); a1 += __shfl_xor(a1, 2);
    if (q == 0) {
        float d = dis[nd];
        float e0 = fast_tanh(fmaf(a0, d, b2[0]));
        float e1 = fast_tanh(fmaf(a1, d, b2[1]));
        float z = fmaf(e0, Wc[0], fmaf(e1, Wc[1], bc[0]));
        out[nd] = __builtin_amdgcn_rcpf(1.f + __expf(-z));
    }
}

extern "C" void kernel_launch(void* const* d_in, const int* in_sizes, int n_in,
                              void* d_out, int out_size, void* d_ws, size_t ws_size,
                              hipStream_t stream) {
    const float* x  = (const float*)d_in[0];
    const int*   ei = (const int*)d_in[1];   // [2, E] as int32
    const float* W1 = (const float*)d_in[2];
    const float* b1 = (const float*)d_in[3];
    const float* W2 = (const float*)d_in[4];
    const float* b2 = (const float*)d_in[5];
    const float* Wc = (const float*)d_in[6];
    const float* bc = (const float*)d_in[7];

    const int n = in_sizes[0] / IN_DIM;
    const int E = in_sizes[1] / 2;
    const int* row = ei;
    const int* col = ei + E;
    const int nbuk = (n + NPB - 1) / NPB;        // 782 (<=1024)
    const int nbukR = nbuk + 1;
    const int nblk = (E + CHUNK - 1) / CHUNK;    // 782 (<=1024)
    const int nblkP = (nblk + 3) & ~3;

    // workspace layout, 512B-aligned slices
    char* w = (char*)d_ws;
    auto alloc = [&](size_t bytes) {
        char* p = w;
        w += (bytes + 511) & ~(size_t)511;
        return p;
    };
    unsigned*       pairsA = (unsigned*)alloc((size_t)nblk * CHUNK * 4);
    unsigned short* chk    = (unsigned short*)alloc((size_t)nblk * nbukR * 2);
    unsigned short* chkT   = (unsigned short*)alloc((size_t)nbukR * nblkP * 2);
    unsigned*       pairs2 = (unsigned*)alloc((size_t)nbuk * CAP * 4);
    unsigned*       offsG  = (unsigned*)alloc((size_t)nbuk * (NPB + 1) * 4);
    float*          dis    = (float*)alloc((size_t)n * 4);
    ushort*         W1p    = (ushort*)alloc(16 * 64 * 8 * 2);
    _Float16*       h1s    = (_Float16*)alloc((size_t)n * HID * 2);
    float*          es     = (float*)alloc((size_t)n * 2 * 4);

    k_packW   <<<32, 256, 0, stream>>>(W1, W1p);
    k_binpairs<<<nblk, 512, 0, stream>>>(row, col, pairsA, chk, E, nbuk);
    {
        dim3 g((nblk + 31) / 32, (nbukR + 31) / 32);
        k_tr<<<g, 256, 0, stream>>>(chk, chkT, nblk, nbukR, nblkP);
    }
    k_sort    <<<nbuk, 512, 0, stream>>>(pairsA, chkT, pairs2, offsG, dis,
                                         nblk, nblkP, nbuk, n);
    k_gemm1   <<<(n + 63) / 64, 256, 0, stream>>>(x, W1p, dis, h1s, n);
    k_gather1 <<<(n + 31) / 32, 256, 0, stream>>>(pairs2, offsG, h1s, dis, b1, W2, es, n);
    k_pass2b  <<<nbuk, 512, 0, stream>>>(pairs2, offsG, es, dis, b2, Wc, bc,
                                         (float*)d_out, n);
}